// Round 2
// baseline (2934.594 us; speedup 1.0000x reference)
//
#include <hip/hip_runtime.h>
#include <cstdint>
#include <cstddef>

#define B_DIM 128
#define T_LEN 2048
#define C_DIM 128
#define NSTEP (T_LEN - 1)   // 2047 backpointer rows, s = 0..2046
#define NS4   512           // ceil(2047/4) dword-rows per batch

// Forward Viterbi. One block per batch, 256 threads = 4 waves, ONE barrier/step.
// Wave w, lane l: q = l>>4 owns i in [32q, 32q+32); m = l&15 owns
// j0 = 32w+m and j1 = 32w+16+m. Partials combined in-wave via shfl_xor(16,32),
// lower-i wins ties (matches jnp.argmax first-index).
// trans slices (64 floats) in registers -- launch_bounds(256,1) prevents spill.
__global__ __launch_bounds__(256, 1) void viterbi_fwd(
    const float* __restrict__ pot,
    const float* __restrict__ trans,
    unsigned* __restrict__ bp4,        // [NS4][B][C] dwords, 4 steps packed/dword
    int* __restrict__ lastTag)
{
    const int b   = blockIdx.x;
    const int tid = threadIdx.x;
    const int w   = tid >> 6;
    const int l   = tid & 63;
    const int q   = l >> 4;            // i-quarter
    const int m   = l & 15;
    const int j0  = 32 * w + m;
    const int j1  = j0 + 16;
    const int ibase = 32 * q;

    // skewed alpha: f(j) = j + 4*(j>>5); double-buffered. 144 floats each.
    __shared__ __align__(16) float alpha[2][144];
    // pot staged 16 steps at a time, double-buffered (16*128 floats each).
    __shared__ __align__(16) float potbuf[2][16 * C_DIM];

    float tr0[32], tr1[32];
#pragma unroll
    for (int k = 0; k < 32; ++k) {
        tr0[k] = trans[(ibase + k) * C_DIM + j0];
        tr1[k] = trans[(ibase + k) * C_DIM + j1];
    }

    const float* potb = pot + (size_t)b * T_LEN * C_DIM;

    // alpha0 = pot[:,0] into buf[1] (step t=1 reads buf[t&1]=buf[1])
    if (tid < C_DIM) alpha[1][tid + 4 * (tid >> 5)] = potb[tid];
    {   // stage pot rows t=0..15 into potbuf[0] (row 0 unused, harmless)
        float4 c0 = *(const float4*)(potb + tid * 8);
        float4 c1 = *(const float4*)(potb + tid * 8 + 4);
        *(float4*)&potbuf[0][tid * 8]     = c0;
        *(float4*)&potbuf[0][tid * 8 + 4] = c1;
    }
    __syncthreads();

    unsigned pack0 = 0, pack1 = 0;

    for (int t = 1; t < T_LEN; ++t) {
        const float* acur = alpha[t & 1];

        // issue staging loads early (consumed by ds_write at end of step)
        float4 s0, s1;
        const bool doStage = ((t & 15) == 15) && (t + 1 < T_LEN);
        if (doStage) {
            const float* src = potb + (t + 1) * C_DIM + tid * 8;
            s0 = *(const float4*)(src);
            s1 = *(const float4*)(src + 4);
        }

        // my 32 alpha values (broadcast b128 reads; skew keeps quarters on
        // disjoint banks: base bank = 4q + 4e)
        float a[32];
#pragma unroll
        for (int e = 0; e < 8; ++e)
            *(float4*)&a[4 * e] = *(const float4*)&acur[36 * q + 4 * e];

        // 4 independent chains of 8 per j (breaks the serial fmax chain)
        float bv0[4], bv1[4];
        int   bi0[4], bi1[4];
#pragma unroll
        for (int c = 0; c < 4; ++c) {
            bv0[c] = -INFINITY; bv1[c] = -INFINITY; bi0[c] = 0; bi1[c] = 0;
        }
#pragma unroll
        for (int c = 0; c < 4; ++c) {
#pragma unroll
            for (int u = 0; u < 8; ++u) {
                const int k = 8 * c + u;
                const float s0v = a[k] + tr0[k];
                if (s0v > bv0[c]) { bv0[c] = s0v; bi0[c] = ibase + k; }
                const float s1v = a[k] + tr1[k];
                if (s1v > bv1[c]) { bv1[c] = s1v; bi1[c] = ibase + k; }
            }
        }
        // merge chains ascending (strict > keeps lowest i)
        float v0 = bv0[0], v1 = bv1[0];
        int   x0 = bi0[0], x1 = bi1[0];
#pragma unroll
        for (int c = 1; c < 4; ++c) {
            if (bv0[c] > v0) { v0 = bv0[c]; x0 = bi0[c]; }
            if (bv1[c] > v1) { v1 = bv1[c]; x1 = bi1[c]; }
        }

        // cross-lane combine: partner q^1 (mask 16), then q^2 (mask 32).
        // plow = partner covers lower i -> partner wins exact ties.
#pragma unroll
        for (int r = 0; r < 2; ++r) {
            const int mask = 16 << r;
            const bool plow = (q >> r) & 1;
            float pv0 = __shfl_xor(v0, mask);
            int   px0 = __shfl_xor(x0, mask);
            if ((pv0 > v0) || (plow && (pv0 == v0))) { v0 = pv0; x0 = px0; }
            float pv1 = __shfl_xor(v1, mask);
            int   px1 = __shfl_xor(x1, mask);
            if ((pv1 > v1) || (plow && (pv1 == v1))) { v1 = pv1; x1 = px1; }
        }

        // final: lanes q==0 add pot, write next alpha + packed bp
        const float* pr = &potbuf[(t >> 4) & 1][(t & 15) * C_DIM];
        if (q == 0) {
            const float p0 = pr[j0];
            const float p1 = pr[j1];
            float* anx = alpha[(t + 1) & 1];
            anx[j0 + 4 * w] = v0 + p0;   // f(j0), j0>>5 == w
            anx[j1 + 4 * w] = v1 + p1;   // f(j1), j1>>5 == w
            const int s  = t - 1;
            const int sh = (s & 3) * 8;
            pack0 |= (unsigned)x0 << sh;
            pack1 |= (unsigned)x1 << sh;
            if ((s & 3) == 3 || t == T_LEN - 1) {
                unsigned* dst = bp4 + ((size_t)(s >> 2) * B_DIM + b) * C_DIM;
                dst[j0] = pack0;
                dst[j1] = pack1;
                pack0 = 0; pack1 = 0;
            }
        }
        if (doStage) {
            const int nb = ((t >> 4) + 1) & 1;
            *(float4*)&potbuf[nb][tid * 8]     = s0;
            *(float4*)&potbuf[nb][tid * 8 + 4] = s1;
        }
        __syncthreads();
    }

    // final alpha is in buf[(2047+1)&1] = buf[0]
    if (tid == 0) {
        float best = alpha[0][0];
        int bx = 0;
        for (int j = 1; j < C_DIM; ++j) {
            const float vv = alpha[0][j + 4 * (j >> 5)];
            if (vv > best) { best = vv; bx = j; }
        }
        lastTag[b] = bx;
    }
}

// Backtrack. One wave per batch. bp row (128 dwords = 16 steps' bytes /4) held
// 2 dwords/lane; cur = byte of row[cur] via 2 ds_bpermute + select.
// 4-deep named-register prefetch queue hides HBM latency.
__global__ __launch_bounds__(64, 1) void viterbi_bwd(
    const unsigned* __restrict__ bp4,
    const int* __restrict__ lastTag,
    float* __restrict__ out)
{
    const int b = blockIdx.x;
    const int l = threadIdx.x;
    float* outb = out + (size_t)b * T_LEN;

    unsigned qa0 = 0, qb0 = 0, qa1 = 0, qb1 = 0,
             qa2 = 0, qb2 = 0, qa3 = 0, qb3 = 0;

    auto ld = [&](int s4, unsigned& A, unsigned& B) {
        if (s4 >= 0) {
            const unsigned* r = bp4 + ((size_t)s4 * B_DIM + b) * C_DIM;
            A = r[l];
            B = r[l + 64];
        }
    };
    ld(511, qa0, qb0);
    ld(510, qa1, qb1);
    ld(509, qa2, qb2);
    ld(508, qa3, qb3);

    int cur = lastTag[b];

    auto ext = [&](unsigned rA, unsigned rB, int c, int byte) -> int {
        const int addr = (c & 63) << 2;
        const int vA = __builtin_amdgcn_ds_bpermute(addr, (int)rA);
        const int vB = __builtin_amdgcn_ds_bpermute(addr, (int)rB);
        const int v = (c & 64) ? vB : vA;
        return (v >> (byte * 8)) & 0xFF;
    };

    // peel s4 = 511: s = 2046..2044 (byte 3 unused); out[2047] = lastTag
    {
        const unsigned rA = qa0, rB = qb0;
        const float t3 = (float)cur;               // out[2047]
        cur = ext(rA, rB, cur, 2); const float t2 = (float)cur;
        cur = ext(rA, rB, cur, 1); const float t1 = (float)cur;
        cur = ext(rA, rB, cur, 0); const float t0 = (float)cur;
        if (l == 0) *(float4*)(outb + 4 * 511) = make_float4(t0, t1, t2, t3);
        qa0 = qa1; qb0 = qb1; qa1 = qa2; qb1 = qb2; qa2 = qa3; qb2 = qb3;
        ld(507, qa3, qb3);
    }

    for (int s4 = 510; s4 >= 0; --s4) {
        const unsigned rA = qa0, rB = qb0;
        cur = ext(rA, rB, cur, 3); const float t3 = (float)cur;
        cur = ext(rA, rB, cur, 2); const float t2 = (float)cur;
        cur = ext(rA, rB, cur, 1); const float t1 = (float)cur;
        cur = ext(rA, rB, cur, 0); const float t0 = (float)cur;
        if (l == 0) *(float4*)(outb + 4 * s4) = make_float4(t0, t1, t2, t3);
        qa0 = qa1; qb0 = qb1; qa1 = qa2; qb1 = qb2; qa2 = qa3; qb2 = qb3;
        ld(s4 - 4, qa3, qb3);
    }
}

extern "C" void kernel_launch(void* const* d_in, const int* in_sizes, int n_in,
                              void* d_out, int out_size, void* d_ws, size_t ws_size,
                              hipStream_t stream)
{
    const float* pot   = (const float*)d_in[0];   // [128, 2048, 128] f32
    const float* trans = (const float*)d_in[1];   // [128, 128] f32
    float* out = (float*)d_out;                   // [128, 2048] f32 (tags)

    // ws: bp4 dwords [512][128][128] (32 MiB) then lastTag int[128]
    unsigned* bp4 = (unsigned*)d_ws;
    int* lastTag  = (int*)((char*)d_ws + (size_t)NS4 * B_DIM * C_DIM * 4);

    viterbi_fwd<<<B_DIM, 256, 0, stream>>>(pot, trans, bp4, lastTag);
    viterbi_bwd<<<B_DIM, 64, 0, stream>>>(bp4, lastTag, out);
}

// Round 3
// 2051.742 us; speedup vs baseline: 1.4303x; 1.4303x over previous
//
#include <hip/hip_runtime.h>
#include <cstdint>
#include <cstddef>

#define B_DIM 128
#define T_LEN 2048
#define C_DIM 128
#define NSTEP (T_LEN - 1)   // 2047 backpointer rows, s = 0..2046
#define NS4   512           // ceil(2047/4) dword-rows per batch

// Forward Viterbi. One block per batch, 1024 threads = 16 waves (4/SIMD).
// Thread (g = tid>>7, j = tid&127) owns i in [16g, 16g+16) for one output j:
// only 16 trans floats per thread -> no spill (the R1/R2 killer).
// Per step: phase1 all threads compute partial (max, argmax) over their 16 i,
// write float2{val, idx} to LDS; barrier; phase2 (256 threads, 32 lanes on
// each of waves 0..3 = all 4 SIMDs) merges 8 partials per j in ascending-g
// order (strict > keeps lowest i = jnp.argmax first-index), adds pot, writes
// alpha and packed backpointers; barrier.
__global__ __launch_bounds__(1024, 4) void viterbi_fwd(
    const float* __restrict__ pot,
    const float* __restrict__ trans,
    unsigned* __restrict__ bp4,        // [NS4][B][C] dwords, 4 steps packed/dword
    int* __restrict__ lastTag)
{
    const int b   = blockIdx.x;
    const int tid = threadIdx.x;
    const int g   = tid >> 7;          // 0..7, i-range [16g, 16g+16)
    const int j   = tid & 127;
    const int ib  = 16 * g;

    __shared__ __align__(16) float  alpha[C_DIM];
    __shared__ __align__(16) float2 pk[8][C_DIM];   // 8 KB partials

    // 16 trans registers
    float tr[16];
#pragma unroll
    for (int k = 0; k < 16; ++k)
        tr[k] = trans[(ib + k) * C_DIM + j];

    const float* potb = pot + (size_t)b * T_LEN * C_DIM;

    // combiner role: waves 0..3 (one per SIMD), lanes 0..31 of each
    const int  lane = tid & 63;
    const bool comb = (tid < 256) && (lane < 32);
    const int  cj   = (tid >> 6) * 32 + lane;       // column this combiner owns

    if (tid < C_DIM) alpha[tid] = potb[tid];        // alpha0 = pot[:,0]
    float pc = 0.0f;
    if (comb) pc = potb[C_DIM + cj];                // pot[t=1][cj]
    unsigned pack = 0;
    __syncthreads();

    for (int t = 1; t < T_LEN; ++t) {
        // prefetch next pot row early (consumed next iteration)
        float pn = 0.0f;
        if (comb && (t + 1 < T_LEN)) pn = potb[(t + 1) * C_DIM + cj];

        // ---- phase 1: partial max/argmax over my 16 i ----
        const float4* a4 = (const float4*)&alpha[ib];   // broadcast b128 reads
        const float4 A0 = a4[0], A1 = a4[1], A2 = a4[2], A3 = a4[3];
        float best = -INFINITY;
        int   bx   = 0;
#define VSTEP(av, kk) do { const float s_ = (av) + tr[kk]; \
        if (s_ > best) { best = s_; bx = ib + (kk); } } while (0)
        VSTEP(A0.x, 0);  VSTEP(A0.y, 1);  VSTEP(A0.z, 2);  VSTEP(A0.w, 3);
        VSTEP(A1.x, 4);  VSTEP(A1.y, 5);  VSTEP(A1.z, 6);  VSTEP(A1.w, 7);
        VSTEP(A2.x, 8);  VSTEP(A2.y, 9);  VSTEP(A2.z, 10); VSTEP(A2.w, 11);
        VSTEP(A3.x, 12); VSTEP(A3.y, 13); VSTEP(A3.z, 14); VSTEP(A3.w, 15);
#undef VSTEP
        pk[g][j] = make_float2(best, __int_as_float(bx));
        __syncthreads();

        // ---- phase 2: 8-way merge per column, ascending g ----
        if (comb) {
            const float2 K0 = pk[0][cj]; const float2 K1 = pk[1][cj];
            const float2 K2 = pk[2][cj]; const float2 K3 = pk[3][cj];
            const float2 K4 = pk[4][cj]; const float2 K5 = pk[5][cj];
            const float2 K6 = pk[6][cj]; const float2 K7 = pk[7][cj];
            float bv = K0.x; int bi = __float_as_int(K0.y);
#define MRG(KK) do { if ((KK).x > bv) { bv = (KK).x; bi = __float_as_int((KK).y); } } while (0)
            MRG(K1); MRG(K2); MRG(K3); MRG(K4); MRG(K5); MRG(K6); MRG(K7);
#undef MRG
            alpha[cj] = bv + pc;
            const int s  = t - 1;
            pack |= (unsigned)bi << ((s & 3) * 8);
            if ((s & 3) == 3 || t == T_LEN - 1) {
                bp4[((size_t)(s >> 2) * B_DIM + b) * C_DIM + cj] = pack;
                pack = 0;
            }
            pc = pn;
        }
        __syncthreads();
    }

    // last_tag = first-index argmax of final alpha (wave 0 shuffle reduce)
    if (tid < 64) {
        const float v0 = alpha[tid], v1 = alpha[tid + 64];
        float v = v0; int x = tid;
        if (v1 > v0) { v = v1; x = tid + 64; }
#pragma unroll
        for (int mk = 1; mk < 64; mk <<= 1) {
            const float pv = __shfl_xor(v, mk);
            const int   px = __shfl_xor(x, mk);
            if (pv > v || (pv == v && px < x)) { v = pv; x = px; }
        }
        if (tid == 0) lastTag[b] = x;
    }
}

// Backtrack. One wave per batch. bp row (128 dwords = 16 steps' bytes /4) held
// 2 dwords/lane; cur = byte of row[cur] via 2 ds_bpermute + select.
// 4-deep named-register prefetch queue hides HBM latency.
__global__ __launch_bounds__(64, 1) void viterbi_bwd(
    const unsigned* __restrict__ bp4,
    const int* __restrict__ lastTag,
    float* __restrict__ out)
{
    const int b = blockIdx.x;
    const int l = threadIdx.x;
    float* outb = out + (size_t)b * T_LEN;

    unsigned qa0 = 0, qb0 = 0, qa1 = 0, qb1 = 0,
             qa2 = 0, qb2 = 0, qa3 = 0, qb3 = 0;

    auto ld = [&](int s4, unsigned& A, unsigned& B) {
        if (s4 >= 0) {
            const unsigned* r = bp4 + ((size_t)s4 * B_DIM + b) * C_DIM;
            A = r[l];
            B = r[l + 64];
        }
    };
    ld(511, qa0, qb0);
    ld(510, qa1, qb1);
    ld(509, qa2, qb2);
    ld(508, qa3, qb3);

    int cur = lastTag[b];

    auto ext = [&](unsigned rA, unsigned rB, int c, int byte) -> int {
        const int addr = (c & 63) << 2;
        const int vA = __builtin_amdgcn_ds_bpermute(addr, (int)rA);
        const int vB = __builtin_amdgcn_ds_bpermute(addr, (int)rB);
        const int v = (c & 64) ? vB : vA;
        return (v >> (byte * 8)) & 0xFF;
    };

    // peel s4 = 511: s = 2046..2044 (byte 3 unused); out[2047] = lastTag
    {
        const unsigned rA = qa0, rB = qb0;
        const float t3 = (float)cur;               // out[2047]
        cur = ext(rA, rB, cur, 2); const float t2 = (float)cur;
        cur = ext(rA, rB, cur, 1); const float t1 = (float)cur;
        cur = ext(rA, rB, cur, 0); const float t0 = (float)cur;
        if (l == 0) *(float4*)(outb + 4 * 511) = make_float4(t0, t1, t2, t3);
        qa0 = qa1; qb0 = qb1; qa1 = qa2; qb1 = qb2; qa2 = qa3; qb2 = qb3;
        ld(507, qa3, qb3);
    }

    for (int s4 = 510; s4 >= 0; --s4) {
        const unsigned rA = qa0, rB = qb0;
        cur = ext(rA, rB, cur, 3); const float t3 = (float)cur;
        cur = ext(rA, rB, cur, 2); const float t2 = (float)cur;
        cur = ext(rA, rB, cur, 1); const float t1 = (float)cur;
        cur = ext(rA, rB, cur, 0); const float t0 = (float)cur;
        if (l == 0) *(float4*)(outb + 4 * s4) = make_float4(t0, t1, t2, t3);
        qa0 = qa1; qb0 = qb1; qa1 = qa2; qb1 = qb2; qa2 = qa3; qb2 = qb3;
        ld(s4 - 4, qa3, qb3);
    }
}

extern "C" void kernel_launch(void* const* d_in, const int* in_sizes, int n_in,
                              void* d_out, int out_size, void* d_ws, size_t ws_size,
                              hipStream_t stream)
{
    const float* pot   = (const float*)d_in[0];   // [128, 2048, 128] f32
    const float* trans = (const float*)d_in[1];   // [128, 128] f32
    float* out = (float*)d_out;                   // [128, 2048] f32 (tags)

    // ws: bp4 dwords [512][128][128] (32 MiB) then lastTag int[128]
    unsigned* bp4 = (unsigned*)d_ws;
    int* lastTag  = (int*)((char*)d_ws + (size_t)NS4 * B_DIM * C_DIM * 4);

    viterbi_fwd<<<B_DIM, 1024, 0, stream>>>(pot, trans, bp4, lastTag);
    viterbi_bwd<<<B_DIM, 64, 0, stream>>>(bp4, lastTag, out);
}

// Round 4
// 1848.620 us; speedup vs baseline: 1.5875x; 1.1099x over previous
//
#include <hip/hip_runtime.h>
#include <cstdint>
#include <cstddef>

#define B_DIM 128
#define T_LEN 2048
#define C_DIM 128
#define NSTEP (T_LEN - 1)   // 2047 backpointer rows, s = 0..2046
#define NS4   512           // ceil(2047/4) dword-rows per batch

// Skew: F(x) = x + 8*(x>>5). 32-float chunk c sits at 40c; the 4 chunks'
// ds_read_b128 streams hit disjoint bank quartets (perfect 32-bank perm).
#define FSKEW(x) ((x) + 8 * ((x) >> 5))

// Forward Viterbi. One block per batch, 512 threads = 8 waves (2/SIMD).
// Wave w owns j in [16w, 16w+16); lane l: j = 16w + (l>>2), d = l&3,
// i in [32d, 32d+32). trans slice (32 floats) in registers. Per step:
// 32 adds + adjacent-pair tournament (thread-local argmax, first-index
// exact) + 2 shfl_xor merge stages (partner-with-lower-d wins ties) +
// d==0 lanes write alpha/bp. Alpha double-buffered -> ONE barrier/step.
__global__ __launch_bounds__(512, 2) void viterbi_fwd(
    const float* __restrict__ pot,
    const float* __restrict__ trans,
    unsigned* __restrict__ bp4,        // [NS4][B][C] dwords, 4 steps packed/dword
    int* __restrict__ lastTag)
{
    const int b   = blockIdx.x;
    const int tid = threadIdx.x;
    const int w   = tid >> 6;
    const int l   = tid & 63;
    const int d   = l & 3;             // i-chunk: [32d, 32d+32)
    const int j   = 16 * w + (l >> 2);
    const int fj  = FSKEW(j);
    const int ib  = 32 * d;

    __shared__ __align__(16) float alphabuf[2][160];

    float tr[32];
#pragma unroll
    for (int k = 0; k < 32; ++k)
        tr[k] = trans[(ib + k) * C_DIM + j];

    const float* potb = pot + (size_t)b * T_LEN * C_DIM;

    // alpha0 = pot[:,0] into buf[1] (step t=1 reads buf[t&1] = buf[1])
    if (tid < C_DIM) alphabuf[1][FSKEW(tid)] = potb[tid];

    // pot prefetch queue, depth 4 (d==0 lanes only consume it)
    float pq0 = 0.f, pq1 = 0.f, pq2 = 0.f, pq3 = 0.f;
    if (d == 0) {
        pq0 = potb[1 * C_DIM + j];
        pq1 = potb[2 * C_DIM + j];
        pq2 = potb[3 * C_DIM + j];
        pq3 = potb[4 * C_DIM + j];
    }
    unsigned pack = 0;
    __syncthreads();

#define STEP(T_, C_, PQ_)                                                     \
    {                                                                         \
        const float* ac_ = &alphabuf[(T_) & 1][40 * d];                       \
        float a_[32];                                                         \
        _Pragma("unroll")                                                     \
        for (int e_ = 0; e_ < 8; ++e_)                                        \
            *(float4*)&a_[4 * e_] = *(const float4*)&ac_[4 * e_];             \
        float s_[32];                                                         \
        _Pragma("unroll")                                                     \
        for (int k_ = 0; k_ < 32; ++k_) s_[k_] = a_[k_] + tr[k_];             \
        float v16_[16]; int x16_[16];                                         \
        _Pragma("unroll")                                                     \
        for (int p_ = 0; p_ < 16; ++p_) {                                     \
            const bool g_ = s_[2 * p_ + 1] > s_[2 * p_];                      \
            v16_[p_] = g_ ? s_[2 * p_ + 1] : s_[2 * p_];                      \
            x16_[p_] = g_ ? 2 * p_ + 1 : 2 * p_;                              \
        }                                                                     \
        float v8_[8]; int x8_[8];                                             \
        _Pragma("unroll")                                                     \
        for (int p_ = 0; p_ < 8; ++p_) {                                      \
            const bool g_ = v16_[2 * p_ + 1] > v16_[2 * p_];                  \
            v8_[p_] = g_ ? v16_[2 * p_ + 1] : v16_[2 * p_];                   \
            x8_[p_] = g_ ? x16_[2 * p_ + 1] : x16_[2 * p_];                   \
        }                                                                     \
        float v4_[4]; int x4_[4];                                             \
        _Pragma("unroll")                                                     \
        for (int p_ = 0; p_ < 4; ++p_) {                                      \
            const bool g_ = v8_[2 * p_ + 1] > v8_[2 * p_];                    \
            v4_[p_] = g_ ? v8_[2 * p_ + 1] : v8_[2 * p_];                     \
            x4_[p_] = g_ ? x8_[2 * p_ + 1] : x8_[2 * p_];                     \
        }                                                                     \
        float v2_[2]; int x2_[2];                                             \
        _Pragma("unroll")                                                     \
        for (int p_ = 0; p_ < 2; ++p_) {                                      \
            const bool g_ = v4_[2 * p_ + 1] > v4_[2 * p_];                    \
            v2_[p_] = g_ ? v4_[2 * p_ + 1] : v4_[2 * p_];                     \
            x2_[p_] = g_ ? x4_[2 * p_ + 1] : x4_[2 * p_];                     \
        }                                                                     \
        const bool gf_ = v2_[1] > v2_[0];                                     \
        float v_ = gf_ ? v2_[1] : v2_[0];                                     \
        int   x_ = ib + (gf_ ? x2_[1] : x2_[0]);                              \
        _Pragma("unroll")                                                     \
        for (int r_ = 0; r_ < 2; ++r_) {                                      \
            const float pv_ = __shfl_xor(v_, 1 << r_);                        \
            const int   px_ = __shfl_xor(x_, 1 << r_);                        \
            const bool  pl_ = (d >> r_) & 1;                                  \
            const bool  tk_ = (pv_ > v_) || (pl_ && (pv_ == v_));             \
            if (tk_) { v_ = pv_; x_ = px_; }                                  \
        }                                                                     \
        if (d == 0) {                                                         \
            alphabuf[((T_) + 1) & 1][fj] = v_ + (PQ_);                        \
            pack |= (unsigned)x_ << (8 * (C_));                               \
            if ((C_) == 3) {                                                  \
                bp4[((size_t)(((T_) - 1) >> 2) * B_DIM + b) * C_DIM + j] =    \
                    pack;                                                     \
                pack = 0;                                                     \
            }                                                                 \
            if ((T_) + 4 < T_LEN) PQ_ = potb[((T_) + 4) * C_DIM + j];         \
        }                                                                     \
        __syncthreads();                                                      \
    }

    // main loop: t = 1 .. 2044 (511 groups of 4, complete bp dwords)
    for (int t = 1; t < 2045; t += 4) {
        STEP(t + 0, 0, pq0)
        STEP(t + 1, 1, pq1)
        STEP(t + 2, 2, pq2)
        STEP(t + 3, 3, pq3)
    }
    // tail: t = 2045, 2046, 2047 (s = 2044..2046 -> bytes 0..2 of dword 511)
    STEP(2045, 0, pq0)
    STEP(2046, 1, pq1)
    STEP(2047, 2, pq2)
    if (d == 0)
        bp4[((size_t)511 * B_DIM + b) * C_DIM + j] = pack;
#undef STEP

    // last_tag = first-index argmax of final alpha (in buf[0]), wave 0
    if (tid < 64) {
        const float* af = alphabuf[0];
        const float v0 = af[FSKEW(tid)];
        const float v1 = af[FSKEW(tid + 64)];
        float v = v0; int x = tid;
        if (v1 > v0) { v = v1; x = tid + 64; }
#pragma unroll
        for (int mk = 1; mk < 64; mk <<= 1) {
            const float pv = __shfl_xor(v, mk);
            const int   px = __shfl_xor(x, mk);
            if (pv > v || (pv == v && px < x)) { v = pv; x = px; }
        }
        if (tid == 0) lastTag[b] = x;
    }
}

// Backtrack. One wave per batch. bp row (128 dwords = 16 steps' bytes /4) held
// 2 dwords/lane; cur = byte of row[cur] via 2 ds_bpermute + select.
// 4-deep named-register prefetch queue hides HBM latency.
__global__ __launch_bounds__(64, 1) void viterbi_bwd(
    const unsigned* __restrict__ bp4,
    const int* __restrict__ lastTag,
    float* __restrict__ out)
{
    const int b = blockIdx.x;
    const int l = threadIdx.x;
    float* outb = out + (size_t)b * T_LEN;

    unsigned qa0 = 0, qb0 = 0, qa1 = 0, qb1 = 0,
             qa2 = 0, qb2 = 0, qa3 = 0, qb3 = 0;

    auto ld = [&](int s4, unsigned& A, unsigned& B) {
        if (s4 >= 0) {
            const unsigned* r = bp4 + ((size_t)s4 * B_DIM + b) * C_DIM;
            A = r[l];
            B = r[l + 64];
        }
    };
    ld(511, qa0, qb0);
    ld(510, qa1, qb1);
    ld(509, qa2, qb2);
    ld(508, qa3, qb3);

    int cur = lastTag[b];

    auto ext = [&](unsigned rA, unsigned rB, int c, int byte) -> int {
        const int addr = (c & 63) << 2;
        const int vA = __builtin_amdgcn_ds_bpermute(addr, (int)rA);
        const int vB = __builtin_amdgcn_ds_bpermute(addr, (int)rB);
        const int v = (c & 64) ? vB : vA;
        return (v >> (byte * 8)) & 0xFF;
    };

    // peel s4 = 511: s = 2046..2044 (byte 3 unused); out[2047] = lastTag
    {
        const unsigned rA = qa0, rB = qb0;
        const float t3 = (float)cur;               // out[2047]
        cur = ext(rA, rB, cur, 2); const float t2 = (float)cur;
        cur = ext(rA, rB, cur, 1); const float t1 = (float)cur;
        cur = ext(rA, rB, cur, 0); const float t0 = (float)cur;
        if (l == 0) *(float4*)(outb + 4 * 511) = make_float4(t0, t1, t2, t3);
        qa0 = qa1; qb0 = qb1; qa1 = qa2; qb1 = qb2; qa2 = qa3; qb2 = qb3;
        ld(507, qa3, qb3);
    }

    for (int s4 = 510; s4 >= 0; --s4) {
        const unsigned rA = qa0, rB = qb0;
        cur = ext(rA, rB, cur, 3); const float t3 = (float)cur;
        cur = ext(rA, rB, cur, 2); const float t2 = (float)cur;
        cur = ext(rA, rB, cur, 1); const float t1 = (float)cur;
        cur = ext(rA, rB, cur, 0); const float t0 = (float)cur;
        if (l == 0) *(float4*)(outb + 4 * s4) = make_float4(t0, t1, t2, t3);
        qa0 = qa1; qb0 = qb1; qa1 = qa2; qb1 = qb2; qa2 = qa3; qb2 = qb3;
        ld(s4 - 4, qa3, qb3);
    }
}

extern "C" void kernel_launch(void* const* d_in, const int* in_sizes, int n_in,
                              void* d_out, int out_size, void* d_ws, size_t ws_size,
                              hipStream_t stream)
{
    const float* pot   = (const float*)d_in[0];   // [128, 2048, 128] f32
    const float* trans = (const float*)d_in[1];   // [128, 128] f32
    float* out = (float*)d_out;                   // [128, 2048] f32 (tags)

    // ws: bp4 dwords [512][128][128] (32 MiB) then lastTag int[128]
    unsigned* bp4 = (unsigned*)d_ws;
    int* lastTag  = (int*)((char*)d_ws + (size_t)NS4 * B_DIM * C_DIM * 4);

    viterbi_fwd<<<B_DIM, 512, 0, stream>>>(pot, trans, bp4, lastTag);
    viterbi_bwd<<<B_DIM, 64, 0, stream>>>(bp4, lastTag, out);
}

// Round 5
// 1843.231 us; speedup vs baseline: 1.5921x; 1.0029x over previous
//
#include <hip/hip_runtime.h>
#include <cstdint>
#include <cstddef>

#define B_DIM 128
#define T_LEN 2048
#define C_DIM 128
#define NSTEP (T_LEN - 1)   // 2047 backpointer rows, s = 0..2046
#define NS4   512           // ceil(2047/4) dword-rows per batch

// Skew: F(x) = x + 8*(x>>5). 32-float chunk c sits at 40c; the 4 chunks'
// ds_read_b128 streams hit disjoint bank quartets (perfect 32-bank perm).
#define FSKEW(x) ((x) + 8 * ((x) >> 5))

// 32 trans values as NAMED SCALARS -- R1..R4 all had the compiler spill the
// tr[] array to scratch (VGPR_Count 32..84, impossible to hold tr+alpha),
// re-fetching 128 B/thread/step. Named scalars + waves_per_eu(2,2) (budget
// 256 VGPR, no occupancy incentive to spill) force register residency.
#define TR_LIST(X) \
    X(0)  X(1)  X(2)  X(3)  X(4)  X(5)  X(6)  X(7)  \
    X(8)  X(9)  X(10) X(11) X(12) X(13) X(14) X(15) \
    X(16) X(17) X(18) X(19) X(20) X(21) X(22) X(23) \
    X(24) X(25) X(26) X(27) X(28) X(29) X(30) X(31)

// Forward Viterbi. One block per batch, 512 threads = 8 waves (2/SIMD).
// Wave w owns j in [16w, 16w+16); lane l: j = 16w + (l>>2), d = l&3,
// i in [32d, 32d+32). trans slice (32 floats) in registers. Per step:
// 32 adds + adjacent-pair tournament (thread-local argmax, first-index
// exact) + 2 shfl_xor merge stages (partner-with-lower-d wins ties) +
// d==0 lanes write alpha/bp. Alpha double-buffered -> ONE barrier/step.
__global__ __launch_bounds__(512)
__attribute__((amdgpu_waves_per_eu(2, 2)))
void viterbi_fwd(
    const float* __restrict__ pot,
    const float* __restrict__ trans,
    unsigned* __restrict__ bp4,        // [NS4][B][C] dwords, 4 steps packed/dword
    int* __restrict__ lastTag)
{
    const int b   = blockIdx.x;
    const int tid = threadIdx.x;
    const int w   = tid >> 6;
    const int l   = tid & 63;
    const int d   = l & 3;             // i-chunk: [32d, 32d+32)
    const int j   = 16 * w + (l >> 2);
    const int fj  = FSKEW(j);
    const int ib  = 32 * d;

    __shared__ __align__(16) float alphabuf[2][160];

#define DECL_TR(K) float tr_##K = trans[(ib + (K)) * C_DIM + j];
    TR_LIST(DECL_TR)
#undef DECL_TR

    const float* potb = pot + (size_t)b * T_LEN * C_DIM;

    // alpha0 = pot[:,0] into buf[1] (step t=1 reads buf[t&1] = buf[1])
    if (tid < C_DIM) alphabuf[1][FSKEW(tid)] = potb[tid];

    // pot prefetch queue, depth 4 (d==0 lanes only consume it)
    float pq0 = 0.f, pq1 = 0.f, pq2 = 0.f, pq3 = 0.f;
    if (d == 0) {
        pq0 = potb[1 * C_DIM + j];
        pq1 = potb[2 * C_DIM + j];
        pq2 = potb[3 * C_DIM + j];
        pq3 = potb[4 * C_DIM + j];
    }
    unsigned pack = 0;
    __syncthreads();

#define ADD_TR(K) s_[K] = a_[K] + tr_##K;

#define STEP(T_, C_, PQ_)                                                     \
    {                                                                         \
        const float* ac_ = &alphabuf[(T_) & 1][40 * d];                       \
        float a_[32];                                                         \
        _Pragma("unroll")                                                     \
        for (int e_ = 0; e_ < 8; ++e_)                                        \
            *(float4*)&a_[4 * e_] = *(const float4*)&ac_[4 * e_];             \
        float s_[32];                                                         \
        TR_LIST(ADD_TR)                                                       \
        float v16_[16]; int x16_[16];                                         \
        _Pragma("unroll")                                                     \
        for (int p_ = 0; p_ < 16; ++p_) {                                     \
            const bool g_ = s_[2 * p_ + 1] > s_[2 * p_];                      \
            v16_[p_] = g_ ? s_[2 * p_ + 1] : s_[2 * p_];                      \
            x16_[p_] = g_ ? 2 * p_ + 1 : 2 * p_;                              \
        }                                                                     \
        float v8_[8]; int x8_[8];                                             \
        _Pragma("unroll")                                                     \
        for (int p_ = 0; p_ < 8; ++p_) {                                      \
            const bool g_ = v16_[2 * p_ + 1] > v16_[2 * p_];                  \
            v8_[p_] = g_ ? v16_[2 * p_ + 1] : v16_[2 * p_];                   \
            x8_[p_] = g_ ? x16_[2 * p_ + 1] : x16_[2 * p_];                   \
        }                                                                     \
        float v4_[4]; int x4_[4];                                             \
        _Pragma("unroll")                                                     \
        for (int p_ = 0; p_ < 4; ++p_) {                                      \
            const bool g_ = v8_[2 * p_ + 1] > v8_[2 * p_];                    \
            v4_[p_] = g_ ? v8_[2 * p_ + 1] : v8_[2 * p_];                     \
            x4_[p_] = g_ ? x8_[2 * p_ + 1] : x8_[2 * p_];                     \
        }                                                                     \
        float v2_[2]; int x2_[2];                                             \
        _Pragma("unroll")                                                     \
        for (int p_ = 0; p_ < 2; ++p_) {                                      \
            const bool g_ = v4_[2 * p_ + 1] > v4_[2 * p_];                    \
            v2_[p_] = g_ ? v4_[2 * p_ + 1] : v4_[2 * p_];                     \
            x2_[p_] = g_ ? x4_[2 * p_ + 1] : x4_[2 * p_];                     \
        }                                                                     \
        const bool gf_ = v2_[1] > v2_[0];                                     \
        float v_ = gf_ ? v2_[1] : v2_[0];                                     \
        int   x_ = ib + (gf_ ? x2_[1] : x2_[0]);                              \
        _Pragma("unroll")                                                     \
        for (int r_ = 0; r_ < 2; ++r_) {                                      \
            const float pv_ = __shfl_xor(v_, 1 << r_);                        \
            const int   px_ = __shfl_xor(x_, 1 << r_);                        \
            const bool  pl_ = (d >> r_) & 1;                                  \
            const bool  tk_ = (pv_ > v_) || (pl_ && (pv_ == v_));             \
            if (tk_) { v_ = pv_; x_ = px_; }                                  \
        }                                                                     \
        if (d == 0) {                                                         \
            alphabuf[((T_) + 1) & 1][fj] = v_ + (PQ_);                        \
            pack |= (unsigned)x_ << (8 * (C_));                               \
            if ((C_) == 3) {                                                  \
                bp4[((size_t)(((T_) - 1) >> 2) * B_DIM + b) * C_DIM + j] =    \
                    pack;                                                     \
                pack = 0;                                                     \
            }                                                                 \
            if ((T_) + 4 < T_LEN) PQ_ = potb[((T_) + 4) * C_DIM + j];         \
        }                                                                     \
        __syncthreads();                                                      \
    }

    // main loop: t = 1 .. 2044 (511 groups of 4, complete bp dwords)
    for (int t = 1; t < 2045; t += 4) {
        STEP(t + 0, 0, pq0)
        STEP(t + 1, 1, pq1)
        STEP(t + 2, 2, pq2)
        STEP(t + 3, 3, pq3)
    }
    // tail: t = 2045, 2046, 2047 (s = 2044..2046 -> bytes 0..2 of dword 511)
    STEP(2045, 0, pq0)
    STEP(2046, 1, pq1)
    STEP(2047, 2, pq2)
    if (d == 0)
        bp4[((size_t)511 * B_DIM + b) * C_DIM + j] = pack;
#undef STEP
#undef ADD_TR

    // last_tag = first-index argmax of final alpha (in buf[0]), wave 0
    if (tid < 64) {
        const float* af = alphabuf[0];
        const float v0 = af[FSKEW(tid)];
        const float v1 = af[FSKEW(tid + 64)];
        float v = v0; int x = tid;
        if (v1 > v0) { v = v1; x = tid + 64; }
#pragma unroll
        for (int mk = 1; mk < 64; mk <<= 1) {
            const float pv = __shfl_xor(v, mk);
            const int   px = __shfl_xor(x, mk);
            if (pv > v || (pv == v && px < x)) { v = pv; x = px; }
        }
        if (tid == 0) lastTag[b] = x;
    }
}

// Backtrack. One wave per batch. bp row (128 dwords = 16 steps' bytes /4) held
// 2 dwords/lane; cur = byte of row[cur] via 2 ds_bpermute + select.
// 4-deep named-register prefetch queue hides HBM latency.
__global__ __launch_bounds__(64, 1) void viterbi_bwd(
    const unsigned* __restrict__ bp4,
    const int* __restrict__ lastTag,
    float* __restrict__ out)
{
    const int b = blockIdx.x;
    const int l = threadIdx.x;
    float* outb = out + (size_t)b * T_LEN;

    unsigned qa0 = 0, qb0 = 0, qa1 = 0, qb1 = 0,
             qa2 = 0, qb2 = 0, qa3 = 0, qb3 = 0;

    auto ld = [&](int s4, unsigned& A, unsigned& B) {
        if (s4 >= 0) {
            const unsigned* r = bp4 + ((size_t)s4 * B_DIM + b) * C_DIM;
            A = r[l];
            B = r[l + 64];
        }
    };
    ld(511, qa0, qb0);
    ld(510, qa1, qb1);
    ld(509, qa2, qb2);
    ld(508, qa3, qb3);

    int cur = lastTag[b];

    auto ext = [&](unsigned rA, unsigned rB, int c, int byte) -> int {
        const int addr = (c & 63) << 2;
        const int vA = __builtin_amdgcn_ds_bpermute(addr, (int)rA);
        const int vB = __builtin_amdgcn_ds_bpermute(addr, (int)rB);
        const int v = (c & 64) ? vB : vA;
        return (v >> (byte * 8)) & 0xFF;
    };

    // peel s4 = 511: s = 2046..2044 (byte 3 unused); out[2047] = lastTag
    {
        const unsigned rA = qa0, rB = qb0;
        const float t3 = (float)cur;               // out[2047]
        cur = ext(rA, rB, cur, 2); const float t2 = (float)cur;
        cur = ext(rA, rB, cur, 1); const float t1 = (float)cur;
        cur = ext(rA, rB, cur, 0); const float t0 = (float)cur;
        if (l == 0) *(float4*)(outb + 4 * 511) = make_float4(t0, t1, t2, t3);
        qa0 = qa1; qb0 = qb1; qa1 = qa2; qb1 = qb2; qa2 = qa3; qb2 = qb3;
        ld(507, qa3, qb3);
    }

    for (int s4 = 510; s4 >= 0; --s4) {
        const unsigned rA = qa0, rB = qb0;
        cur = ext(rA, rB, cur, 3); const float t3 = (float)cur;
        cur = ext(rA, rB, cur, 2); const float t2 = (float)cur;
        cur = ext(rA, rB, cur, 1); const float t1 = (float)cur;
        cur = ext(rA, rB, cur, 0); const float t0 = (float)cur;
        if (l == 0) *(float4*)(outb + 4 * s4) = make_float4(t0, t1, t2, t3);
        qa0 = qa1; qb0 = qb1; qa1 = qa2; qb1 = qb2; qa2 = qa3; qb2 = qb3;
        ld(s4 - 4, qa3, qb3);
    }
}

extern "C" void kernel_launch(void* const* d_in, const int* in_sizes, int n_in,
                              void* d_out, int out_size, void* d_ws, size_t ws_size,
                              hipStream_t stream)
{
    const float* pot   = (const float*)d_in[0];   // [128, 2048, 128] f32
    const float* trans = (const float*)d_in[1];   // [128, 128] f32
    float* out = (float*)d_out;                   // [128, 2048] f32 (tags)

    // ws: bp4 dwords [512][128][128] (32 MiB) then lastTag int[128]
    unsigned* bp4 = (unsigned*)d_ws;
    int* lastTag  = (int*)((char*)d_ws + (size_t)NS4 * B_DIM * C_DIM * 4);

    viterbi_fwd<<<B_DIM, 512, 0, stream>>>(pot, trans, bp4, lastTag);
    viterbi_bwd<<<B_DIM, 64, 0, stream>>>(bp4, lastTag, out);
}

// Round 7
// 1728.159 us; speedup vs baseline: 1.6981x; 1.0666x over previous
//
#include <hip/hip_runtime.h>
#include <cstdint>
#include <cstddef>

#define B_DIM 128
#define T_LEN 2048
#define C_DIM 128
#define NSTEP (T_LEN - 1)   // 2047 backpointer rows, s = 0..2046
#define NS4   512           // ceil(2047/4) dword-rows per batch

// Skew: F(x) = x + 8*(x>>5). 32-float chunk c sits at 40c; the 4 chunks'
// ds_read_b128 streams hit disjoint bank quartets (perfect 32-bank perm).
#define FSKEW(x) ((x) + 8 * ((x) >> 5))

// Barrier WITHOUT vmcnt drain: __syncthreads() emits
// s_waitcnt vmcnt(0) lgkmcnt(0) before s_barrier, draining the in-flight
// pot prefetch + bp store every step (~1200 cyc/step dead time, the
// R1..R5-invariant bottleneck). Cross-wave LDS visibility only needs
// lgkmcnt(0). Global loads/stores stay in flight across the barrier;
// the compiler inserts precise vmcnt(N) waits at the point of use.
#define LDS_BARRIER() asm volatile("s_waitcnt lgkmcnt(0)\n\ts_barrier" ::: "memory")

// 32 trans values as NAMED SCALARS (R5: VGPR=88, resident, keep).
#define TR_LIST(X) \
    X(0)  X(1)  X(2)  X(3)  X(4)  X(5)  X(6)  X(7)  \
    X(8)  X(9)  X(10) X(11) X(12) X(13) X(14) X(15) \
    X(16) X(17) X(18) X(19) X(20) X(21) X(22) X(23) \
    X(24) X(25) X(26) X(27) X(28) X(29) X(30) X(31)

// Forward Viterbi. One block per batch, 512 threads = 8 waves (2/SIMD).
// Wave w owns j in [16w, 16w+16); lane l: j = 16w + (l>>2), d = l&3,
// i in [32d, 32d+32). Per step: 32 adds + adjacent-pair tournament
// (first-index exact) + 2 DPP quad_perm merge rounds (xor1: 0xB1,
// xor2: 0x4E; partner-with-lower-d wins ties) + d==0 lanes write
// alpha/bp. Alpha double-buffered -> ONE lgkm-only barrier/step.
__global__ __launch_bounds__(512)
__attribute__((amdgpu_waves_per_eu(2, 2)))
void viterbi_fwd(
    const float* __restrict__ pot,
    const float* __restrict__ trans,
    unsigned* __restrict__ bp4,        // [NS4][B][C] dwords, 4 steps packed/dword
    int* __restrict__ lastTag)
{
    const int b   = blockIdx.x;
    const int tid = threadIdx.x;
    const int w   = tid >> 6;
    const int l   = tid & 63;
    const int d   = l & 3;             // i-chunk: [32d, 32d+32)
    const int j   = 16 * w + (l >> 2);
    const int fj  = FSKEW(j);
    const int ib  = 32 * d;

    __shared__ __align__(16) float alphabuf[2][160];

#define DECL_TR(K) float tr_##K = trans[(ib + (K)) * C_DIM + j];
    TR_LIST(DECL_TR)
#undef DECL_TR

    const float* potb = pot + (size_t)b * T_LEN * C_DIM;

    // alpha0 = pot[:,0] into buf[1] (step t=1 reads buf[t&1] = buf[1])
    if (tid < C_DIM) alphabuf[1][FSKEW(tid)] = potb[tid];

    // pot prefetch queue, depth 4 (d==0 lanes only consume it)
    float pq0 = 0.f, pq1 = 0.f, pq2 = 0.f, pq3 = 0.f;
    if (d == 0) {
        pq0 = potb[1 * C_DIM + j];
        pq1 = potb[2 * C_DIM + j];
        pq2 = potb[3 * C_DIM + j];
        pq3 = potb[4 * C_DIM + j];
    }
    unsigned pack = 0;
    __syncthreads();   // init barrier: full drain once, fine

#define ADD_TR(K) s_[K] = a_[K] + tr_##K;

#define STEP(T_, C_, PQ_)                                                     \
    {                                                                         \
        const float* ac_ = &alphabuf[(T_) & 1][40 * d];                       \
        float a_[32];                                                         \
        _Pragma("unroll")                                                     \
        for (int e_ = 0; e_ < 8; ++e_)                                        \
            *(float4*)&a_[4 * e_] = *(const float4*)&ac_[4 * e_];             \
        float s_[32];                                                         \
        TR_LIST(ADD_TR)                                                       \
        float v16_[16]; int x16_[16];                                         \
        _Pragma("unroll")                                                     \
        for (int p_ = 0; p_ < 16; ++p_) {                                     \
            const bool g_ = s_[2 * p_ + 1] > s_[2 * p_];                      \
            v16_[p_] = g_ ? s_[2 * p_ + 1] : s_[2 * p_];                      \
            x16_[p_] = g_ ? 2 * p_ + 1 : 2 * p_;                              \
        }                                                                     \
        float v8_[8]; int x8_[8];                                             \
        _Pragma("unroll")                                                     \
        for (int p_ = 0; p_ < 8; ++p_) {                                      \
            const bool g_ = v16_[2 * p_ + 1] > v16_[2 * p_];                  \
            v8_[p_] = g_ ? v16_[2 * p_ + 1] : v16_[2 * p_];                   \
            x8_[p_] = g_ ? x16_[2 * p_ + 1] : x16_[2 * p_];                   \
        }                                                                     \
        float v4_[4]; int x4_[4];                                             \
        _Pragma("unroll")                                                     \
        for (int p_ = 0; p_ < 4; ++p_) {                                      \
            const bool g_ = v8_[2 * p_ + 1] > v8_[2 * p_];                    \
            v4_[p_] = g_ ? v8_[2 * p_ + 1] : v8_[2 * p_];                     \
            x4_[p_] = g_ ? x8_[2 * p_ + 1] : x8_[2 * p_];                     \
        }                                                                     \
        float v2_[2]; int x2_[2];                                             \
        _Pragma("unroll")                                                     \
        for (int p_ = 0; p_ < 2; ++p_) {                                      \
            const bool g_ = v4_[2 * p_ + 1] > v4_[2 * p_];                    \
            v2_[p_] = g_ ? v4_[2 * p_ + 1] : v4_[2 * p_];                     \
            x2_[p_] = g_ ? x4_[2 * p_ + 1] : x4_[2 * p_];                     \
        }                                                                     \
        const bool gf_ = v2_[1] > v2_[0];                                     \
        float v_ = gf_ ? v2_[1] : v2_[0];                                     \
        int   x_ = ib + (gf_ ? x2_[1] : x2_[0]);                              \
        /* DPP quad_perm merge across d. Round 1: xor 1 (ctrl 0xB1) */        \
        {                                                                     \
            const float pv_ = __int_as_float(__builtin_amdgcn_update_dpp(     \
                0, __float_as_int(v_), 0xB1, 0xF, 0xF, true));                \
            const int   px_ = __builtin_amdgcn_update_dpp(                    \
                0, x_, 0xB1, 0xF, 0xF, true);                                 \
            const bool  pl_ = d & 1;                                          \
            const bool  tk_ = (pv_ > v_) || (pl_ && (pv_ == v_));             \
            if (tk_) { v_ = pv_; x_ = px_; }                                  \
        }                                                                     \
        /* Round 2: xor 2 (ctrl 0x4E) */                                      \
        {                                                                     \
            const float pv_ = __int_as_float(__builtin_amdgcn_update_dpp(     \
                0, __float_as_int(v_), 0x4E, 0xF, 0xF, true));                \
            const int   px_ = __builtin_amdgcn_update_dpp(                    \
                0, x_, 0x4E, 0xF, 0xF, true);                                 \
            const bool  pl_ = (d >> 1) & 1;                                   \
            const bool  tk_ = (pv_ > v_) || (pl_ && (pv_ == v_));             \
            if (tk_) { v_ = pv_; x_ = px_; }                                  \
        }                                                                     \
        if (d == 0) {                                                         \
            alphabuf[((T_) + 1) & 1][fj] = v_ + (PQ_);                        \
            pack |= (unsigned)x_ << (8 * (C_));                               \
            if ((C_) == 3) {                                                  \
                bp4[((size_t)(((T_) - 1) >> 2) * B_DIM + b) * C_DIM + j] =    \
                    pack;                                                     \
                pack = 0;                                                     \
            }                                                                 \
            if ((T_) + 4 < T_LEN) PQ_ = potb[((T_) + 4) * C_DIM + j];         \
        }                                                                     \
        LDS_BARRIER();                                                        \
    }

    // main loop: t = 1 .. 2044 (511 groups of 4, complete bp dwords)
    for (int t = 1; t < 2045; t += 4) {
        STEP(t + 0, 0, pq0)
        STEP(t + 1, 1, pq1)
        STEP(t + 2, 2, pq2)
        STEP(t + 3, 3, pq3)
    }
    // tail: t = 2045, 2046, 2047 (s = 2044..2046 -> bytes 0..2 of dword 511)
    STEP(2045, 0, pq0)
    STEP(2046, 1, pq1)
    STEP(2047, 2, pq2)
    if (d == 0)
        bp4[((size_t)511 * B_DIM + b) * C_DIM + j] = pack;
#undef STEP
#undef ADD_TR

    // last_tag = first-index argmax of final alpha (in buf[0]), wave 0
    if (tid < 64) {
        const float* af = alphabuf[0];
        const float v0 = af[FSKEW(tid)];
        const float v1 = af[FSKEW(tid + 64)];
        float v = v0; int x = tid;
        if (v1 > v0) { v = v1; x = tid + 64; }
#pragma unroll
        for (int mk = 1; mk < 64; mk <<= 1) {
            const float pv = __shfl_xor(v, mk);
            const int   px = __shfl_xor(x, mk);
            if (pv > v || (pv == v && px < x)) { v = pv; x = px; }
        }
        if (tid == 0) lastTag[b] = x;
    }
}

// Backtrack. One wave per batch. bp row (128 dwords = 16 steps' bytes /4) held
// 2 dwords/lane; cur = byte of row[cur] via 2 ds_bpermute + select.
// 4-deep named-register prefetch queue hides HBM latency.
__global__ __launch_bounds__(64, 1) void viterbi_bwd(
    const unsigned* __restrict__ bp4,
    const int* __restrict__ lastTag,
    float* __restrict__ out)
{
    const int b = blockIdx.x;
    const int l = threadIdx.x;
    float* outb = out + (size_t)b * T_LEN;

    unsigned qa0 = 0, qb0 = 0, qa1 = 0, qb1 = 0,
             qa2 = 0, qb2 = 0, qa3 = 0, qb3 = 0;

    auto ld = [&](int s4, unsigned& A, unsigned& B) {
        if (s4 >= 0) {
            const unsigned* r = bp4 + ((size_t)s4 * B_DIM + b) * C_DIM;
            A = r[l];
            B = r[l + 64];
        }
    };
    ld(511, qa0, qb0);
    ld(510, qa1, qb1);
    ld(509, qa2, qb2);
    ld(508, qa3, qb3);

    int cur = lastTag[b];

    auto ext = [&](unsigned rA, unsigned rB, int c, int byte) -> int {
        const int addr = (c & 63) << 2;
        const int vA = __builtin_amdgcn_ds_bpermute(addr, (int)rA);
        const int vB = __builtin_amdgcn_ds_bpermute(addr, (int)rB);
        const int v = (c & 64) ? vB : vA;
        return (v >> (byte * 8)) & 0xFF;
    };

    // peel s4 = 511: s = 2046..2044 (byte 3 unused); out[2047] = lastTag
    {
        const unsigned rA = qa0, rB = qb0;
        const float t3 = (float)cur;               // out[2047]
        cur = ext(rA, rB, cur, 2); const float t2 = (float)cur;
        cur = ext(rA, rB, cur, 1); const float t1 = (float)cur;
        cur = ext(rA, rB, cur, 0); const float t0 = (float)cur;
        if (l == 0) *(float4*)(outb + 4 * 511) = make_float4(t0, t1, t2, t3);
        qa0 = qa1; qb0 = qb1; qa1 = qa2; qb1 = qb2; qa2 = qa3; qb2 = qb3;
        ld(507, qa3, qb3);
    }

    for (int s4 = 510; s4 >= 0; --s4) {
        const unsigned rA = qa0, rB = qb0;
        cur = ext(rA, rB, cur, 3); const float t3 = (float)cur;
        cur = ext(rA, rB, cur, 2); const float t2 = (float)cur;
        cur = ext(rA, rB, cur, 1); const float t1 = (float)cur;
        cur = ext(rA, rB, cur, 0); const float t0 = (float)cur;
        if (l == 0) *(float4*)(outb + 4 * s4) = make_float4(t0, t1, t2, t3);
        qa0 = qa1; qb0 = qb1; qa1 = qa2; qb1 = qb2; qa2 = qa3; qb2 = qb3;
        ld(s4 - 4, qa3, qb3);
    }
}

extern "C" void kernel_launch(void* const* d_in, const int* in_sizes, int n_in,
                              void* d_out, int out_size, void* d_ws, size_t ws_size,
                              hipStream_t stream)
{
    const float* pot   = (const float*)d_in[0];   // [128, 2048, 128] f32
    const float* trans = (const float*)d_in[1];   // [128, 128] f32
    float* out = (float*)d_out;                   // [128, 2048] f32 (tags)

    // ws: bp4 dwords [512][128][128] (32 MiB) then lastTag int[128]
    unsigned* bp4 = (unsigned*)d_ws;
    int* lastTag  = (int*)((char*)d_ws + (size_t)NS4 * B_DIM * C_DIM * 4);

    viterbi_fwd<<<B_DIM, 512, 0, stream>>>(pot, trans, bp4, lastTag);
    viterbi_bwd<<<B_DIM, 64, 0, stream>>>(bp4, lastTag, out);
}